// Round 1
// baseline (185.224 us; speedup 1.0000x reference)
//
#include <hip/hip_runtime.h>
#include <hip/hip_bf16.h>

#define EPS 1e-12f

// Kernel 1: one 64-lane wave per row -> inv_norm[i] = 1 / max(||emb_i||, EPS)
__global__ __launch_bounds__(256) void row_inv_norm_kernel(
    const float* __restrict__ emb, float* __restrict__ inv_norm, int N) {
    int gid  = blockIdx.x * blockDim.x + threadIdx.x;
    int row  = gid >> 6;
    int lane = threadIdx.x & 63;
    if (row >= N) return;

    const float2* r = (const float2*)(emb + (size_t)row * 128);
    float2 v = r[lane];                      // 64 lanes x 8B = 512B coalesced
    float s = v.x * v.x + v.y * v.y;
    #pragma unroll
    for (int off = 32; off; off >>= 1) s += __shfl_xor(s, off, 64);
    if (lane == 0) {
        float n = sqrtf(s);
        inv_norm[row] = 1.0f / fmaxf(n, EPS);
    }
}

// Kernel 2: one edge per 32-lane half-wave, float4 loads (512B/row coalesced).
// z[e] = scale * inv[src] * inv[dst] * sum_h emb[src,h]*d[h]*emb[dst,h]
__global__ __launch_bounds__(256) void edge_dot_kernel(
    const float* __restrict__ emb, const float* __restrict__ inv_norm,
    const int* __restrict__ src, const int* __restrict__ dst,
    const float* __restrict__ d, const float* __restrict__ scale,
    float* __restrict__ out, int E) {
    int gid  = blockIdx.x * blockDim.x + threadIdx.x;
    int lane = threadIdx.x & 63;
    int half = lane >> 5;          // which of the 2 edges this wave handles
    int sl   = lane & 31;          // sub-lane within the half-wave
    int e    = ((gid >> 6) << 1) + half;

    // per-lane d fragment (uniform across edges)
    float4 dv = ((const float4*)d)[sl];

    float p = 0.0f;
    int si = 0, di = 0;
    if (e < E) {
        si = src[e];               // same-address broadcast within half-wave
        di = dst[e];
        const float4* ra = (const float4*)(emb + (size_t)si * 128);
        const float4* rb = (const float4*)(emb + (size_t)di * 128);
        float4 a = ra[sl];         // 32 lanes x 16B = 512B contiguous
        float4 b = rb[sl];
        p = a.x * b.x * dv.x + a.y * b.y * dv.y
          + a.z * b.z * dv.z + a.w * b.w * dv.w;
    }
    // reduce across the 32-lane half (xor masks <32 stay within the half)
    #pragma unroll
    for (int off = 16; off; off >>= 1) p += __shfl_xor(p, off, 64);

    if (sl == 0 && e < E) {
        out[e] = p * inv_norm[si] * inv_norm[di] * scale[0];
    }
}

extern "C" void kernel_launch(void* const* d_in, const int* in_sizes, int n_in,
                              void* d_out, int out_size, void* d_ws, size_t ws_size,
                              hipStream_t stream) {
    const float* emb   = (const float*)d_in[0];   // [N,128] fp32
    const int*   src   = (const int*)d_in[1];     // [E]
    const int*   dst   = (const int*)d_in[2];     // [E]
    const float* d     = (const float*)d_in[3];   // [128]
    const float* scale = (const float*)d_in[4];   // [1]
    float*       out   = (float*)d_out;           // [E]

    int N = in_sizes[0] / 128;
    int E = in_sizes[1];

    float* inv_norm = (float*)d_ws;               // N floats = 400 KB scratch

    // Kernel 1: 4 rows per 256-thread block
    {
        int rows_per_block = 256 / 64;
        int blocks = (N + rows_per_block - 1) / rows_per_block;
        row_inv_norm_kernel<<<blocks, 256, 0, stream>>>(emb, inv_norm, N);
    }
    // Kernel 2: 8 edges per 256-thread block (2 per wave)
    {
        int edges_per_block = (256 / 64) * 2;
        int blocks = (E + edges_per_block - 1) / edges_per_block;
        edge_dot_kernel<<<blocks, 256, 0, stream>>>(emb, inv_norm, src, dst,
                                                    d, scale, out, E);
    }
}

// Round 2
// 139.680 us; speedup vs baseline: 1.3261x; 1.3261x over previous
//
#include <hip/hip_runtime.h>
#include <hip/hip_bf16.h>
#include <hip/hip_fp16.h>

#define EPS 1e-12f

// ---------- Path A: fp16 normalized table in d_ws ----------

// One 64-lane wave per row: compute 1/max(||row||,EPS), write normalized
// row as fp16 (256B per row, coalesced half2 stores).
__global__ __launch_bounds__(256) void normalize_fp16_kernel(
    const float* __restrict__ emb, __half* __restrict__ en, int N) {
    int gid  = blockIdx.x * blockDim.x + threadIdx.x;
    int row  = gid >> 6;
    int lane = threadIdx.x & 63;
    if (row >= N) return;

    const float2* r = (const float2*)(emb + (size_t)row * 128);
    float2 v = r[lane];                       // 64 lanes x 8B = 512B coalesced
    float s = v.x * v.x + v.y * v.y;
    #pragma unroll
    for (int off = 32; off; off >>= 1) s += __shfl_xor(s, off, 64);
    float inv = 1.0f / fmaxf(sqrtf(s), EPS);

    __half2* w = (__half2*)(en + (size_t)row * 128);
    w[lane] = __float22half2_rn(make_float2(v.x * inv, v.y * inv));
}

// One edge per 16-lane group (4 edges/wave). Each lane loads 16B (8 halves)
// of the src row and dst row -> 256B/row coalesced. fp32 accumulate.
__global__ __launch_bounds__(256) void edge_dot_fp16_kernel(
    const __half* __restrict__ en,
    const int* __restrict__ src, const int* __restrict__ dst,
    const float* __restrict__ d, const float* __restrict__ scale,
    float* __restrict__ out, int E) {
    int gid  = blockIdx.x * blockDim.x + threadIdx.x;
    int lane = threadIdx.x & 63;
    int sub  = lane >> 4;          // which of 4 edges in this wave
    int sl   = lane & 15;          // sub-lane within the 16-lane group
    int e    = ((gid >> 6) << 2) + sub;

    // d fragment: elements [sl*8, sl*8+8), fp32
    float4 d0 = ((const float4*)d)[sl * 2];
    float4 d1 = ((const float4*)d)[sl * 2 + 1];
    float dd[8] = {d0.x, d0.y, d0.z, d0.w, d1.x, d1.y, d1.z, d1.w};

    float p = 0.0f;
    if (e < E) {
        int si = src[e];           // broadcast within 16-lane group
        int di = dst[e];
        const float4* ra = (const float4*)(en + (size_t)si * 128);
        const float4* rb = (const float4*)(en + (size_t)di * 128);
        float4 a = ra[sl];         // 16 lanes x 16B = 256B contiguous
        float4 b = rb[sl];
        const __half2* ah = (const __half2*)&a;
        const __half2* bh = (const __half2*)&b;
        #pragma unroll
        for (int i = 0; i < 4; ++i) {
            float2 af = __half22float2(ah[i]);
            float2 bf = __half22float2(bh[i]);
            p += af.x * bf.x * dd[2 * i];
            p += af.y * bf.y * dd[2 * i + 1];
        }
    }
    // reduce across the 16-lane group (xor masks < 16 stay in-group)
    #pragma unroll
    for (int off = 8; off; off >>= 1) p += __shfl_xor(p, off, 64);

    if (sl == 0 && e < E) out[e] = p * scale[0];
}

// ---------- Path B (fallback, ws too small): round-1 kernels ----------

__global__ __launch_bounds__(256) void row_inv_norm_kernel(
    const float* __restrict__ emb, float* __restrict__ inv_norm, int N) {
    int gid  = blockIdx.x * blockDim.x + threadIdx.x;
    int row  = gid >> 6;
    int lane = threadIdx.x & 63;
    if (row >= N) return;
    const float2* r = (const float2*)(emb + (size_t)row * 128);
    float2 v = r[lane];
    float s = v.x * v.x + v.y * v.y;
    #pragma unroll
    for (int off = 32; off; off >>= 1) s += __shfl_xor(s, off, 64);
    if (lane == 0) inv_norm[row] = 1.0f / fmaxf(sqrtf(s), EPS);
}

__global__ __launch_bounds__(256) void edge_dot_kernel(
    const float* __restrict__ emb, const float* __restrict__ inv_norm,
    const int* __restrict__ src, const int* __restrict__ dst,
    const float* __restrict__ d, const float* __restrict__ scale,
    float* __restrict__ out, int E) {
    int gid  = blockIdx.x * blockDim.x + threadIdx.x;
    int lane = threadIdx.x & 63;
    int half = lane >> 5;
    int sl   = lane & 31;
    int e    = ((gid >> 6) << 1) + half;
    float4 dv = ((const float4*)d)[sl];
    float p = 0.0f;
    int si = 0, di = 0;
    if (e < E) {
        si = src[e]; di = dst[e];
        const float4* ra = (const float4*)(emb + (size_t)si * 128);
        const float4* rb = (const float4*)(emb + (size_t)di * 128);
        float4 a = ra[sl];
        float4 b = rb[sl];
        p = a.x * b.x * dv.x + a.y * b.y * dv.y
          + a.z * b.z * dv.z + a.w * b.w * dv.w;
    }
    #pragma unroll
    for (int off = 16; off; off >>= 1) p += __shfl_xor(p, off, 64);
    if (sl == 0 && e < E) out[e] = p * inv_norm[si] * inv_norm[di] * scale[0];
}

extern "C" void kernel_launch(void* const* d_in, const int* in_sizes, int n_in,
                              void* d_out, int out_size, void* d_ws, size_t ws_size,
                              hipStream_t stream) {
    const float* emb   = (const float*)d_in[0];   // [N,128] fp32
    const int*   src   = (const int*)d_in[1];     // [E]
    const int*   dst   = (const int*)d_in[2];     // [E]
    const float* d     = (const float*)d_in[3];   // [128]
    const float* scale = (const float*)d_in[4];   // [1]
    float*       out   = (float*)d_out;           // [E]

    int N = in_sizes[0] / 128;
    int E = in_sizes[1];

    size_t need = (size_t)N * 128 * sizeof(__half);   // 25.6 MB
    if (ws_size >= need) {
        __half* en = (__half*)d_ws;
        {   // 4 rows per 256-thread block
            int blocks = (N + 3) / 4;
            normalize_fp16_kernel<<<blocks, 256, 0, stream>>>(emb, en, N);
        }
        {   // 16 edges per 256-thread block (4 per wave)
            int blocks = (E + 15) / 16;
            edge_dot_fp16_kernel<<<blocks, 256, 0, stream>>>(en, src, dst,
                                                             d, scale, out, E);
        }
    } else {
        float* inv_norm = (float*)d_ws;               // N floats
        {
            int blocks = (N + 3) / 4;
            row_inv_norm_kernel<<<blocks, 256, 0, stream>>>(emb, inv_norm, N);
        }
        {
            int blocks = (E + 7) / 8;
            edge_dot_kernel<<<blocks, 256, 0, stream>>>(emb, inv_norm, src, dst,
                                                        d, scale, out, E);
        }
    }
}

// Round 3
// 119.477 us; speedup vs baseline: 1.5503x; 1.1691x over previous
//
#include <hip/hip_runtime.h>
#include <hip/hip_bf16.h>
#include <hip/hip_fp16.h>

#define EPS 1e-12f
// Table stores en * 16 in fp8 e4m3 (OCP, HW cvt on gfx950); epilogue divides by 256.
#define TBL_SCALE 16.0f
#define TBL_SCALE_INV2 (1.0f / 256.0f)

// ---------- Path A: fp8 e4m3 normalized table (x16) in d_ws ----------

// One row per 32-lane half-wave: lane handles 4 elements (float4 load),
// 5-step shfl reduce for the norm, pack 4 fp8 -> one uint store per lane
// (32 lanes x 4B = 128B/row coalesced).
__global__ __launch_bounds__(256) void normalize_fp8_kernel(
    const float* __restrict__ emb, unsigned int* __restrict__ en, int N) {
    int gid  = blockIdx.x * blockDim.x + threadIdx.x;
    int row  = gid >> 5;
    int sl   = threadIdx.x & 31;
    if (row >= N) return;

    float4 v = ((const float4*)(emb + (size_t)row * 128))[sl];
    float s = v.x * v.x + v.y * v.y + v.z * v.z + v.w * v.w;
    #pragma unroll
    for (int off = 16; off; off >>= 1) s += __shfl_xor(s, off, 64);
    float inv = TBL_SCALE / fmaxf(sqrtf(s), EPS);

    int p = 0;
    p = __builtin_amdgcn_cvt_pk_fp8_f32(v.x * inv, v.y * inv, p, false);
    p = __builtin_amdgcn_cvt_pk_fp8_f32(v.z * inv, v.w * inv, p, true);
    en[(size_t)row * 32 + sl] = (unsigned int)p;
}

typedef __attribute__((ext_vector_type(2))) float float2v;

// One edge per 8-lane group (8 edges/wave). Each lane loads one uint4
// (16 fp8) per row -> 128B/row coalesced. HW fp8->f32 unpack, fp32 FMA.
__global__ __launch_bounds__(256) void edge_dot_fp8_kernel(
    const unsigned int* __restrict__ en,
    const int* __restrict__ src, const int* __restrict__ dst,
    const float* __restrict__ d, const float* __restrict__ scale,
    float* __restrict__ out, int E) {
    int gid  = blockIdx.x * blockDim.x + threadIdx.x;
    int lane = threadIdx.x & 63;
    int grp  = lane >> 3;          // 8 edges per wave
    int sl   = lane & 7;           // sub-lane in the 8-lane group
    int e    = ((gid >> 6) << 3) + grp;

    // d fragment: elements [sl*16, sl*16+16), uniform per lane
    float dd[16];
    {
        const float4* dp = (const float4*)d;
        #pragma unroll
        for (int i = 0; i < 4; ++i) {
            float4 t = dp[sl * 4 + i];
            dd[4 * i + 0] = t.x; dd[4 * i + 1] = t.y;
            dd[4 * i + 2] = t.z; dd[4 * i + 3] = t.w;
        }
    }

    float p = 0.0f;
    if (e < E) {
        int si = src[e];
        int di = dst[e];
        uint4 a4 = ((const uint4*)(en + (size_t)si * 32))[sl];  // 8x16B = 128B
        uint4 b4 = ((const uint4*)(en + (size_t)di * 32))[sl];
        const unsigned int* aw = (const unsigned int*)&a4;
        const unsigned int* bw = (const unsigned int*)&b4;
        #pragma unroll
        for (int w = 0; w < 4; ++w) {
            float2v a0 = __builtin_amdgcn_cvt_pk_f32_fp8((int)aw[w], false);
            float2v a1 = __builtin_amdgcn_cvt_pk_f32_fp8((int)aw[w], true);
            float2v b0 = __builtin_amdgcn_cvt_pk_f32_fp8((int)bw[w], false);
            float2v b1 = __builtin_amdgcn_cvt_pk_f32_fp8((int)bw[w], true);
            p += a0.x * b0.x * dd[4 * w + 0];
            p += a0.y * b0.y * dd[4 * w + 1];
            p += a1.x * b1.x * dd[4 * w + 2];
            p += a1.y * b1.y * dd[4 * w + 3];
        }
    }
    // reduce across the 8-lane group (xor masks < 8 stay in-group)
    #pragma unroll
    for (int off = 4; off; off >>= 1) p += __shfl_xor(p, off, 64);

    if (sl == 0 && e < E) out[e] = p * scale[0] * TBL_SCALE_INV2;
}

// ---------- Path B (fallback, ws too small): fp16 table (round-2) ----------

__global__ __launch_bounds__(256) void normalize_fp16_kernel(
    const float* __restrict__ emb, __half* __restrict__ en, int N) {
    int gid  = blockIdx.x * blockDim.x + threadIdx.x;
    int row  = gid >> 6;
    int lane = threadIdx.x & 63;
    if (row >= N) return;
    const float2* r = (const float2*)(emb + (size_t)row * 128);
    float2 v = r[lane];
    float s = v.x * v.x + v.y * v.y;
    #pragma unroll
    for (int off = 32; off; off >>= 1) s += __shfl_xor(s, off, 64);
    float inv = 1.0f / fmaxf(sqrtf(s), EPS);
    __half2* w = (__half2*)(en + (size_t)row * 128);
    w[lane] = __float22half2_rn(make_float2(v.x * inv, v.y * inv));
}

__global__ __launch_bounds__(256) void edge_dot_fp16_kernel(
    const __half* __restrict__ en,
    const int* __restrict__ src, const int* __restrict__ dst,
    const float* __restrict__ d, const float* __restrict__ scale,
    float* __restrict__ out, int E) {
    int gid  = blockIdx.x * blockDim.x + threadIdx.x;
    int lane = threadIdx.x & 63;
    int sub  = lane >> 4;
    int sl   = lane & 15;
    int e    = ((gid >> 6) << 2) + sub;
    float4 d0 = ((const float4*)d)[sl * 2];
    float4 d1 = ((const float4*)d)[sl * 2 + 1];
    float dd[8] = {d0.x, d0.y, d0.z, d0.w, d1.x, d1.y, d1.z, d1.w};
    float p = 0.0f;
    if (e < E) {
        int si = src[e];
        int di = dst[e];
        float4 a = ((const float4*)(en + (size_t)si * 128))[sl];
        float4 b = ((const float4*)(en + (size_t)di * 128))[sl];
        const __half2* ah = (const __half2*)&a;
        const __half2* bh = (const __half2*)&b;
        #pragma unroll
        for (int i = 0; i < 4; ++i) {
            float2 af = __half22float2(ah[i]);
            float2 bf = __half22float2(bh[i]);
            p += af.x * bf.x * dd[2 * i];
            p += af.y * bf.y * dd[2 * i + 1];
        }
    }
    #pragma unroll
    for (int off = 8; off; off >>= 1) p += __shfl_xor(p, off, 64);
    if (sl == 0 && e < E) out[e] = p * scale[0];
}

extern "C" void kernel_launch(void* const* d_in, const int* in_sizes, int n_in,
                              void* d_out, int out_size, void* d_ws, size_t ws_size,
                              hipStream_t stream) {
    const float* emb   = (const float*)d_in[0];   // [N,128] fp32
    const int*   src   = (const int*)d_in[1];     // [E]
    const int*   dst   = (const int*)d_in[2];     // [E]
    const float* d     = (const float*)d_in[3];   // [128]
    const float* scale = (const float*)d_in[4];   // [1]
    float*       out   = (float*)d_out;           // [E]

    int N = in_sizes[0] / 128;
    int E = in_sizes[1];

    size_t need_fp8 = (size_t)N * 128;            // 12.8 MB
    if (ws_size >= need_fp8) {
        unsigned int* en = (unsigned int*)d_ws;
        {   // 8 rows per 256-thread block (1 row / 32-lane half)
            int blocks = (N + 7) / 8;
            normalize_fp8_kernel<<<blocks, 256, 0, stream>>>(emb, en, N);
        }
        {   // 32 edges per 256-thread block (8 per wave)
            int blocks = (E + 31) / 32;
            edge_dot_fp8_kernel<<<blocks, 256, 0, stream>>>(en, src, dst,
                                                            d, scale, out, E);
        }
    } else {
        __half* en = (__half*)d_ws;
        {
            int blocks = (N + 3) / 4;
            normalize_fp16_kernel<<<blocks, 256, 0, stream>>>(emb, en, N);
        }
        {
            int blocks = (E + 15) / 16;
            edge_dot_fp16_kernel<<<blocks, 256, 0, stream>>>(en, src, dst,
                                                             d, scale, out, E);
        }
    }
}